// Round 4
// baseline (363.764 us; speedup 1.0000x reference)
//
#include <hip/hip_runtime.h>
#include <hip/hip_bf16.h>

constexpr int cB = 32;
constexpr int cS = 1024;
constexpr int cD = 1280;
constexpr int KC = 32;          // k-chunk for split-K matmuls
constexpr int NKC = cD / KC;    // 40 k-chunks
constexpr int NNC = cD / 256;   // 5 n-chunks

#define LN_EPS 1e-5f
#define MASK_FILL -1e9f
#define SCALE 0.02795084971874737f   // 1280^-0.5

// ---------------- init outputs with biases (ws is poisoned 0xAA) -------------
__global__ __launch_bounds__(256) void k_init(const float* __restrict__ bq,
                                              const float* __restrict__ bv,
                                              const float* __restrict__ bo,
                                              float* __restrict__ q0,
                                              float* __restrict__ qk,
                                              float* __restrict__ ctx,
                                              float* __restrict__ h) {
    int i = blockIdx.x * 256 + threadIdx.x;    // 0..cB*cD-1
    int n = i % cD;
    q0[i]  = bq[n];
    qk[i]  = 0.f;
    ctx[i] = bv[n];
    h[i]   = bo[n];
}

// ============================================================================
// Split-K matmul, atomic accumulate, B accessed as W^T (W row-major [N,K]):
//   out[b][n] += sum_{k in chunk} A[b, k] * W[n, k]
// W tile staged through LDS (transposed, padded) for coalesced global reads.
// A operands wave-uniform -> scalar loads feeding v_fmac.
// ============================================================================
__global__ __launch_bounds__(256) void k_mmT_p1a(const float* __restrict__ A,
                                                 size_t lda,
                                                 const float* __restrict__ W,
                                                 float* __restrict__ out) {
    __shared__ float s_t[KC * 257];
    int t = threadIdx.x;
    int nc = blockIdx.x % NNC, kc = blockIdx.x / NNC;
    int n0 = nc * 256, k0 = kc * KC;

#pragma unroll
    for (int p = 0; p < 8; ++p) {
        int r  = (t >> 3) + p * 32;        // n_local
        int ko = (t & 7) * 4;              // k_local
        float4 wv = *reinterpret_cast<const float4*>(W + (size_t)(n0 + r) * cD + k0 + ko);
        s_t[(ko + 0) * 257 + r] = wv.x;
        s_t[(ko + 1) * 257 + r] = wv.y;
        s_t[(ko + 2) * 257 + r] = wv.z;
        s_t[(ko + 3) * 257 + r] = wv.w;
    }
    __syncthreads();

    float w[KC];
#pragma unroll
    for (int kk = 0; kk < KC; ++kk) w[kk] = s_t[kk * 257 + t];

#pragma unroll
    for (int b = 0; b < cB; ++b) {
        const float* Ab = A + (size_t)b * lda + k0;   // wave-uniform -> s_load
        float a0 = 0.f, a1 = 0.f, a2 = 0.f, a3 = 0.f;
#pragma unroll
        for (int kk = 0; kk < KC; kk += 4) {
            a0 += Ab[kk + 0] * w[kk + 0];
            a1 += Ab[kk + 1] * w[kk + 1];
            a2 += Ab[kk + 2] * w[kk + 2];
            a3 += Ab[kk + 3] * w[kk + 3];
        }
        atomicAdd(&out[b * cD + n0 + t], (a0 + a1) + (a2 + a3));
    }
}

// ============================================================================
// Split-K matmul, atomic accumulate, B accessed directly (B row-major [K,N]).
// ============================================================================
__global__ __launch_bounds__(256) void k_mm_p1a(const float* __restrict__ A,
                                                size_t lda,
                                                const float* __restrict__ B,
                                                float* __restrict__ out) {
    int t = threadIdx.x;
    int nc = blockIdx.x % NNC, kc = blockIdx.x / NNC;
    int n0 = nc * 256, k0 = kc * KC;

    float w[KC];
#pragma unroll
    for (int kk = 0; kk < KC; ++kk)
        w[kk] = B[(size_t)(k0 + kk) * cD + n0 + t];   // coalesced

#pragma unroll
    for (int b = 0; b < cB; ++b) {
        const float* Ab = A + (size_t)b * lda + k0;   // wave-uniform -> s_load
        float a0 = 0.f, a1 = 0.f, a2 = 0.f, a3 = 0.f;
#pragma unroll
        for (int kk = 0; kk < KC; kk += 4) {
            a0 += Ab[kk + 0] * w[kk + 0];
            a1 += Ab[kk + 1] * w[kk + 1];
            a2 += Ab[kk + 2] * w[kk + 2];
            a3 += Ab[kk + 3] * w[kk + 3];
        }
        atomicAdd(&out[b * cD + n0 + t], (a0 + a1) + (a2 + a3));
    }
}

// ============================================================================
// Fused flash-style: qb + scores + online softmax + weighted emb sum.
// Grid: b*32 + sc ; block 256 = 4 waves ; wave handles 8 consecutive s-rows.
// ============================================================================
__global__ __launch_bounds__(256) void k_attn(const float* __restrict__ emb,
                                              const float* __restrict__ qk,
                                              const float* __restrict__ q0,
                                              const float* __restrict__ bk,
                                              const int* __restrict__ mask,
                                              float* __restrict__ pm,
                                              float* __restrict__ pl,
                                              float* __restrict__ pacc) {
    __shared__ float s_all[4][cD];
    __shared__ float s_m[4], s_l[4], s_qb[4];
    int blk = blockIdx.x;
    int b = blk >> 5, sc = blk & 31;
    int w = threadIdx.x >> 6, lane = threadIdx.x & 63;
    int d0 = lane * 4;

    // ---- qb = q0[b,:] . bk (block-wide) ----
    float pq = 0.f;
#pragma unroll
    for (int j = 0; j < 5; ++j)
        pq += q0[b * cD + j * 256 + threadIdx.x] * bk[j * 256 + threadIdx.x];
#pragma unroll
    for (int off = 32; off; off >>= 1) pq += __shfl_xor(pq, off, 64);
    if (lane == 0) s_qb[w] = pq;

    float4 qkr[5];
#pragma unroll
    for (int it = 0; it < 5; ++it)
        qkr[it] = *reinterpret_cast<const float4*>(qk + b * cD + it * 256 + d0);
    __syncthreads();
    float qbv = s_qb[0] + s_qb[1] + s_qb[2] + s_qb[3];

    float m = -INFINITY, l = 0.f;
    float4 acc[5];
#pragma unroll
    for (int it = 0; it < 5; ++it) acc[it] = make_float4(0.f, 0.f, 0.f, 0.f);

    int s0 = sc * 32 + w * 8;
    for (int r = 0; r < 8; ++r) {
        int s = s0 + r;
        const float* e = emb + (size_t)(b * cS + s) * cD + d0;
        float4 er[5];
#pragma unroll
        for (int it = 0; it < 5; ++it)
            er[it] = *reinterpret_cast<const float4*>(e + it * 256);
        float dot = 0.f;
#pragma unroll
        for (int it = 0; it < 5; ++it)
            dot += er[it].x * qkr[it].x + er[it].y * qkr[it].y
                 + er[it].z * qkr[it].z + er[it].w * qkr[it].w;
#pragma unroll
        for (int off = 32; off; off >>= 1) dot += __shfl_xor(dot, off, 64);
        float scv = (mask[b * cS + s] == 0) ? MASK_FILL : (dot + qbv) * SCALE;
        if (scv > m) {                       // wave-uniform branch
            float f = __expf(m - scv);
            l *= f;
#pragma unroll
            for (int it = 0; it < 5; ++it) {
                acc[it].x *= f; acc[it].y *= f; acc[it].z *= f; acc[it].w *= f;
            }
            m = scv;
        }
        float p = __expf(scv - m);
        l += p;
#pragma unroll
        for (int it = 0; it < 5; ++it) {
            acc[it].x += p * er[it].x; acc[it].y += p * er[it].y;
            acc[it].z += p * er[it].z; acc[it].w += p * er[it].w;
        }
    }

    // ---- block combine: parallel over 4 waves ----
    if (lane == 0) { s_m[w] = m; s_l[w] = l; }
    __syncthreads();
    float M = fmaxf(fmaxf(s_m[0], s_m[1]), fmaxf(s_m[2], s_m[3]));
    float f = __expf(m - M);                 // wave-uniform
#pragma unroll
    for (int it = 0; it < 5; ++it)
        *reinterpret_cast<float4*>(&s_all[w][it * 256 + d0]) =
            make_float4(acc[it].x * f, acc[it].y * f, acc[it].z * f, acc[it].w * f);
    __syncthreads();

    if (threadIdx.x == 0) {
        float lt = s_l[0] * __expf(s_m[0] - M) + s_l[1] * __expf(s_m[1] - M)
                 + s_l[2] * __expf(s_m[2] - M) + s_l[3] * __expf(s_m[3] - M);
        pm[blk] = M; pl[blk] = lt;
    }
#pragma unroll
    for (int j = 0; j < 5; ++j) {
        int d = j * 256 + threadIdx.x;
        pacc[(size_t)blk * cD + d] =
            s_all[0][d] + s_all[1][d] + s_all[2][d] + s_all[3][d];
    }
}

// ---------------- combine 32 partials per batch -> ectx ----------------------
__global__ __launch_bounds__(256) void k_attn_red(const float* __restrict__ pm,
                                                  const float* __restrict__ pl,
                                                  const float* __restrict__ pacc,
                                                  float* __restrict__ ectx) {
    int b = blockIdx.x / 5, j = blockIdx.x % 5;
    int d = j * 256 + threadIdx.x;
    float M = -INFINITY;
    for (int i = 0; i < 32; ++i) M = fmaxf(M, pm[b * 32 + i]);
    float L = 0.f, a = 0.f;
    for (int i = 0; i < 32; ++i) {
        float wf = __expf(pm[b * 32 + i] - M);
        L += pl[b * 32 + i] * wf;
        a += wf * pacc[(size_t)(b * 32 + i) * cD + d];
    }
    ectx[b * cD + d] = a / L;
}

// ---------------- LayerNorm + ReLU -------------------------------------------
__global__ __launch_bounds__(256) void k_ln(const float* __restrict__ h,
                                            const float* __restrict__ gamma,
                                            const float* __restrict__ beta,
                                            float* __restrict__ out) {
    int b = blockIdx.x;
    __shared__ float red[8];
    int wid = threadIdx.x >> 6, lane = threadIdx.x & 63;
    float v[5];
    float sum = 0.f;
#pragma unroll
    for (int j = 0; j < 5; ++j) {
        v[j] = h[b * cD + threadIdx.x + 256 * j];
        sum += v[j];
    }
#pragma unroll
    for (int off = 32; off; off >>= 1) sum += __shfl_xor(sum, off, 64);
    if (lane == 0) red[wid] = sum;
    __syncthreads();
    float mu = (red[0] + red[1] + red[2] + red[3]) * (1.f / cD);
    float vs = 0.f;
#pragma unroll
    for (int j = 0; j < 5; ++j) { float t = v[j] - mu; vs += t * t; }
#pragma unroll
    for (int off = 32; off; off >>= 1) vs += __shfl_xor(vs, off, 64);
    if (lane == 0) red[4 + wid] = vs;
    __syncthreads();
    float var = (red[4] + red[5] + red[6] + red[7]) * (1.f / cD);
    float inv = rsqrtf(var + LN_EPS);
#pragma unroll
    for (int j = 0; j < 5; ++j) {
        int idx = threadIdx.x + 256 * j;
        float o = (v[j] - mu) * inv * gamma[idx] + beta[idx];
        out[b * cD + idx] = fmaxf(o, 0.f);
    }
}

extern "C" void kernel_launch(void* const* d_in, const int* in_sizes, int n_in,
                              void* d_out, int out_size, void* d_ws, size_t ws_size,
                              hipStream_t stream) {
    const float* emb   = (const float*)d_in[0];
    const int*   mask  = (const int*)d_in[1];
    const float* Wq    = (const float*)d_in[2];
    const float* bq    = (const float*)d_in[3];
    const float* Wk    = (const float*)d_in[4];
    const float* bk    = (const float*)d_in[5];
    const float* Wv    = (const float*)d_in[6];
    const float* bv    = (const float*)d_in[7];
    const float* Wo    = (const float*)d_in[8];
    const float* bo    = (const float*)d_in[9];
    const float* gamma = (const float*)d_in[10];
    const float* beta  = (const float*)d_in[11];

    float* ws   = (float*)d_ws;
    float* q0   = ws;                        // 40960
    float* qk   = q0 + cB * cD;              // 40960
    float* ctx  = qk + cB * cD;              // 40960
    float* h    = ctx + cB * cD;             // 40960
    float* pm   = h + cB * cD;               // 1024
    float* pl   = pm + 1024;                 // 1024
    float* pacc = pl + 1024;                 // 1024*1280
    float* ectx = pacc + (size_t)1024 * cD;  // 40960

    const int mmGrid  = NNC * NKC;           // 200
    const int redGrid = cB * cD / 256;       // 160

    // init: q0=bq, qk=0, ctx=bv, h=bo (biases folded into accumulators)
    k_init<<<redGrid, 256, 0, stream>>>(bq, bv, bo, q0, qk, ctx, h);
    // q0 += emb[:,0,:] @ Wq^T
    k_mmT_p1a<<<mmGrid, 256, 0, stream>>>(emb, (size_t)cS * cD, Wq, q0);
    // qk += q0 @ Wk
    k_mm_p1a<<<mmGrid, 256, 0, stream>>>(q0, (size_t)cD, Wk, qk);
    // fused qb + scores + softmax + weighted emb sum
    k_attn<<<cB * 32, 256, 0, stream>>>(emb, qk, q0, bk, mask, pm, pl, pacc);
    k_attn_red<<<redGrid, 256, 0, stream>>>(pm, pl, pacc, ectx);
    // ctx += ectx @ Wv^T
    k_mmT_p1a<<<mmGrid, 256, 0, stream>>>(ectx, (size_t)cD, Wv, ctx);
    // h += ctx @ Wo^T
    k_mmT_p1a<<<mmGrid, 256, 0, stream>>>(ctx, (size_t)cD, Wo, h);
    // LayerNorm + ReLU
    k_ln<<<cB, 256, 0, stream>>>(h, gamma, beta, (float*)d_out);
}

// Round 5
// 345.832 us; speedup vs baseline: 1.0518x; 1.0518x over previous
//
#include <hip/hip_runtime.h>
#include <hip/hip_bf16.h>

constexpr int cB = 32;
constexpr int cS = 1024;
constexpr int cD = 1280;
constexpr int KC = 16;          // k-chunk for split-K qk matmul
constexpr int NKC = cD / KC;    // 80 k-chunks
constexpr int NNC = cD / 256;   // 5 n-chunks

#define LN_EPS 1e-5f
#define MASK_FILL -1e9f
#define SCALE 0.02795084971874737f   // 1280^-0.5

// ============================================================================
// Row-dot matmul vs W^T:  out[b*cD+n] = bias[n] + dot(A[b,:], W[n,:])
// Grid 640 x 256 (2560 waves). Wave owns one W row (read once into regs),
// loops 16 batches with independent loads -> deep ILP, no atomics.
// ============================================================================
__global__ __launch_bounds__(256) void k_dotT(const float* __restrict__ A,
                                              size_t lda,
                                              const float* __restrict__ W,
                                              const float* __restrict__ bias,
                                              float* __restrict__ out) {
    int w = threadIdx.x >> 6, lane = threadIdx.x & 63;
    int gw = blockIdx.x * 4 + w;            // 0..2559
    int n = gw >> 1;                        // W row
    int bh = (gw & 1) * 16;                 // batch half
    int d0 = lane * 4;

    float4 wr[5];
#pragma unroll
    for (int it = 0; it < 5; ++it)
        wr[it] = *reinterpret_cast<const float4*>(W + (size_t)n * cD + it * 256 + d0);
    float bn = bias[n];

#pragma unroll
    for (int bi = 0; bi < 16; ++bi) {
        int b = bh + bi;
        const float* a = A + (size_t)b * lda + d0;
        float4 av[5];
#pragma unroll
        for (int it = 0; it < 5; ++it)
            av[it] = *reinterpret_cast<const float4*>(a + it * 256);
        float dot = 0.f;
#pragma unroll
        for (int it = 0; it < 5; ++it)
            dot += av[it].x * wr[it].x + av[it].y * wr[it].y
                 + av[it].z * wr[it].z + av[it].w * wr[it].w;
#pragma unroll
        for (int off = 32; off; off >>= 1) dot += __shfl_xor(dot, off, 64);
        if (lane == 0) out[b * cD + n] = dot + bn;
    }
}

// ============================================================================
// Split-K phase 1 (no atomics), B row-major [K,N]:
//   part[kc][b][n] = sum_{k in chunk} A[b,k] * B[k,n]
// Grid 400 = 5 nc x 80 kc. A loads wave-uniform -> s_load.
// ============================================================================
__global__ __launch_bounds__(256) void k_mm_p1(const float* __restrict__ A,
                                               const float* __restrict__ B,
                                               float* __restrict__ part) {
    int t = threadIdx.x;
    int nc = blockIdx.x % NNC, kc = blockIdx.x / NNC;
    int n0 = nc * 256, k0 = kc * KC;

    float w[KC];
#pragma unroll
    for (int kk = 0; kk < KC; ++kk)
        w[kk] = B[(size_t)(k0 + kk) * cD + n0 + t];   // coalesced

#pragma unroll
    for (int b = 0; b < cB; ++b) {
        const float* Ab = A + (size_t)b * cD + k0;    // wave-uniform -> s_load
        float a0 = 0.f, a1 = 0.f, a2 = 0.f, a3 = 0.f;
#pragma unroll
        for (int kk = 0; kk < KC; kk += 4) {
            a0 += Ab[kk + 0] * w[kk + 0];
            a1 += Ab[kk + 1] * w[kk + 1];
            a2 += Ab[kk + 2] * w[kk + 2];
            a3 += Ab[kk + 3] * w[kk + 3];
        }
        part[(size_t)kc * (cB * cD) + b * cD + n0 + t] = (a0 + a1) + (a2 + a3);
    }
}

// ---------------- phase 2: qk = sum partials ; last block: qb = q0.bk --------
__global__ __launch_bounds__(256) void k_mm_red_qb(const float* __restrict__ part,
                                                   const float* __restrict__ q0,
                                                   const float* __restrict__ bk,
                                                   float* __restrict__ qk,
                                                   float* __restrict__ qb) {
    if (blockIdx.x < 160) {
        int i = blockIdx.x * 256 + threadIdx.x;       // 0..cB*cD-1
        float s = 0.f;
#pragma unroll
        for (int c = 0; c < NKC; ++c) s += part[(size_t)c * (cB * cD) + i];
        qk[i] = s;
    } else {
        int w = threadIdx.x >> 6, lane = threadIdx.x & 63;
        int d0 = lane * 4;
        float4 bkr[5];
#pragma unroll
        for (int it = 0; it < 5; ++it)
            bkr[it] = *reinterpret_cast<const float4*>(bk + it * 256 + d0);
#pragma unroll
        for (int r = 0; r < 8; ++r) {
            int b = w * 8 + r;
            float dot = 0.f;
#pragma unroll
            for (int it = 0; it < 5; ++it) {
                float4 qv = *reinterpret_cast<const float4*>(q0 + b * cD + it * 256 + d0);
                dot += qv.x * bkr[it].x + qv.y * bkr[it].y
                     + qv.z * bkr[it].z + qv.w * bkr[it].w;
            }
#pragma unroll
            for (int off = 32; off; off >>= 1) dot += __shfl_xor(dot, off, 64);
            if (lane == 0) qb[b] = dot;
        }
    }
}

// ============================================================================
// Fused flash-style: scores + online softmax + weighted emb sum.
// Grid: b*32 + sc ; block 256 = 4 waves ; wave handles 8 consecutive s-rows.
// ============================================================================
__global__ __launch_bounds__(256) void k_attn(const float* __restrict__ emb,
                                              const float* __restrict__ qk,
                                              const float* __restrict__ qb,
                                              const int* __restrict__ mask,
                                              float* __restrict__ pm,
                                              float* __restrict__ pl,
                                              float* __restrict__ pacc) {
    __shared__ float s_all[4][cD];
    __shared__ float s_m[4], s_l[4];
    int blk = blockIdx.x;
    int b = blk >> 5, sc = blk & 31;
    int w = threadIdx.x >> 6, lane = threadIdx.x & 63;
    int d0 = lane * 4;

    float4 qkr[5];
#pragma unroll
    for (int it = 0; it < 5; ++it)
        qkr[it] = *reinterpret_cast<const float4*>(qk + b * cD + it * 256 + d0);
    float qbv = qb[b];

    float m = -INFINITY, l = 0.f;
    float4 acc[5];
#pragma unroll
    for (int it = 0; it < 5; ++it) acc[it] = make_float4(0.f, 0.f, 0.f, 0.f);

    int s0 = sc * 32 + w * 8;
    for (int r = 0; r < 8; ++r) {
        int s = s0 + r;
        const float* e = emb + (size_t)(b * cS + s) * cD + d0;
        float4 er[5];
#pragma unroll
        for (int it = 0; it < 5; ++it)
            er[it] = *reinterpret_cast<const float4*>(e + it * 256);
        float dot = 0.f;
#pragma unroll
        for (int it = 0; it < 5; ++it)
            dot += er[it].x * qkr[it].x + er[it].y * qkr[it].y
                 + er[it].z * qkr[it].z + er[it].w * qkr[it].w;
#pragma unroll
        for (int off = 32; off; off >>= 1) dot += __shfl_xor(dot, off, 64);
        float scv = (mask[b * cS + s] == 0) ? MASK_FILL : (dot + qbv) * SCALE;
        if (scv > m) {                       // wave-uniform (dot is broadcast)
            float f = __expf(m - scv);
            l *= f;
#pragma unroll
            for (int it = 0; it < 5; ++it) {
                acc[it].x *= f; acc[it].y *= f; acc[it].z *= f; acc[it].w *= f;
            }
            m = scv;
        }
        float p = __expf(scv - m);
        l += p;
#pragma unroll
        for (int it = 0; it < 5; ++it) {
            acc[it].x += p * er[it].x; acc[it].y += p * er[it].y;
            acc[it].z += p * er[it].z; acc[it].w += p * er[it].w;
        }
    }

    // ---- block combine: parallel over 4 waves ----
    if (lane == 0) { s_m[w] = m; s_l[w] = l; }
    __syncthreads();
    float M = fmaxf(fmaxf(s_m[0], s_m[1]), fmaxf(s_m[2], s_m[3]));
    float f = __expf(m - M);                 // wave-uniform
#pragma unroll
    for (int it = 0; it < 5; ++it)
        *reinterpret_cast<float4*>(&s_all[w][it * 256 + d0]) =
            make_float4(acc[it].x * f, acc[it].y * f, acc[it].z * f, acc[it].w * f);
    __syncthreads();

    if (threadIdx.x == 0) {
        float lt = s_l[0] * __expf(s_m[0] - M) + s_l[1] * __expf(s_m[1] - M)
                 + s_l[2] * __expf(s_m[2] - M) + s_l[3] * __expf(s_m[3] - M);
        pm[blk] = M; pl[blk] = lt;
    }
#pragma unroll
    for (int j = 0; j < 5; ++j) {
        int d = j * 256 + threadIdx.x;
        pacc[(size_t)blk * cD + d] =
            s_all[0][d] + s_all[1][d] + s_all[2][d] + s_all[3][d];
    }
}

// ---------------- combine 32 partials per batch -> ectx ----------------------
__global__ __launch_bounds__(256) void k_attn_red(const float* __restrict__ pm,
                                                  const float* __restrict__ pl,
                                                  const float* __restrict__ pacc,
                                                  float* __restrict__ ectx) {
    int b = blockIdx.x / 5, j = blockIdx.x % 5;
    int d = j * 256 + threadIdx.x;
    float M = -INFINITY;
    for (int i = 0; i < 32; ++i) M = fmaxf(M, pm[b * 32 + i]);
    float L = 0.f, a = 0.f;
    for (int i = 0; i < 32; ++i) {
        float wf = __expf(pm[b * 32 + i] - M);
        L += pl[b * 32 + i] * wf;
        a += wf * pacc[(size_t)(b * 32 + i) * cD + d];
    }
    ectx[b * cD + d] = a / L;
}

// ---------------- LayerNorm + ReLU -------------------------------------------
__global__ __launch_bounds__(256) void k_ln(const float* __restrict__ h,
                                            const float* __restrict__ gamma,
                                            const float* __restrict__ beta,
                                            float* __restrict__ out) {
    int b = blockIdx.x;
    __shared__ float red[8];
    int wid = threadIdx.x >> 6, lane = threadIdx.x & 63;
    float v[5];
    float sum = 0.f;
#pragma unroll
    for (int j = 0; j < 5; ++j) {
        v[j] = h[b * cD + threadIdx.x + 256 * j];
        sum += v[j];
    }
#pragma unroll
    for (int off = 32; off; off >>= 1) sum += __shfl_xor(sum, off, 64);
    if (lane == 0) red[wid] = sum;
    __syncthreads();
    float mu = (red[0] + red[1] + red[2] + red[3]) * (1.f / cD);
    float vs = 0.f;
#pragma unroll
    for (int j = 0; j < 5; ++j) { float t = v[j] - mu; vs += t * t; }
#pragma unroll
    for (int off = 32; off; off >>= 1) vs += __shfl_xor(vs, off, 64);
    if (lane == 0) red[4 + wid] = vs;
    __syncthreads();
    float var = (red[4] + red[5] + red[6] + red[7]) * (1.f / cD);
    float inv = rsqrtf(var + LN_EPS);
#pragma unroll
    for (int j = 0; j < 5; ++j) {
        int idx = threadIdx.x + 256 * j;
        float o = (v[j] - mu) * inv * gamma[idx] + beta[idx];
        out[b * cD + idx] = fmaxf(o, 0.f);
    }
}

extern "C" void kernel_launch(void* const* d_in, const int* in_sizes, int n_in,
                              void* d_out, int out_size, void* d_ws, size_t ws_size,
                              hipStream_t stream) {
    const float* emb   = (const float*)d_in[0];
    const int*   mask  = (const int*)d_in[1];
    const float* Wq    = (const float*)d_in[2];
    const float* bq    = (const float*)d_in[3];
    const float* Wk    = (const float*)d_in[4];
    const float* bk    = (const float*)d_in[5];
    const float* Wv    = (const float*)d_in[6];
    const float* bv    = (const float*)d_in[7];
    const float* Wo    = (const float*)d_in[8];
    const float* bo    = (const float*)d_in[9];
    const float* gamma = (const float*)d_in[10];
    const float* beta  = (const float*)d_in[11];

    float* ws   = (float*)d_ws;
    float* part = ws;                        // 80*32*1280 = 3,276,800
    float* q0   = part + NKC * cB * cD;      // 40960
    float* qk   = q0 + cB * cD;              // 40960
    float* qb   = qk + cB * cD;              // 32
    float* pm   = qb + cB;                   // 1024
    float* pl   = pm + 1024;                 // 1024
    float* pacc = pl + 1024;                 // 1024*1280
    float* ectx = pacc + (size_t)1024 * cD;  // 40960
    float* ctx  = ectx + cB * cD;            // 40960
    float* h    = ctx + cB * cD;             // 40960

    // q0 = emb[:,0,:] @ Wq^T + bq       (row-dot, 2560 waves)
    k_dotT<<<640, 256, 0, stream>>>(emb, (size_t)cS * cD, Wq, bq, q0);
    // qk = q0 @ Wk  (split-K, 400 blocks, no atomics)
    k_mm_p1<<<NNC * NKC, 256, 0, stream>>>(q0, Wk, part);
    // qk reduce + qb = q0 . bk
    k_mm_red_qb<<<161, 256, 0, stream>>>(part, q0, bk, qk, qb);
    // fused scores + softmax + weighted emb sum
    k_attn<<<cB * 32, 256, 0, stream>>>(emb, qk, qb, mask, pm, pl, pacc);
    k_attn_red<<<160, 256, 0, stream>>>(pm, pl, pacc, ectx);
    // ctx = ectx @ Wv^T + bv            (row-dot)
    k_dotT<<<640, 256, 0, stream>>>(ectx, (size_t)cD, Wv, bv, ctx);
    // h = ctx @ Wo^T + bo               (row-dot)
    k_dotT<<<640, 256, 0, stream>>>(ctx, (size_t)cD, Wo, bo, h);
    // LayerNorm + ReLU
    k_ln<<<cB, 256, 0, stream>>>(h, gamma, beta, (float*)d_out);
}